// Round 2
// baseline (135.269 us; speedup 1.0000x reference)
//
#include <hip/hip_runtime.h>
#include <math.h>

#define T_TOK 16384   // 4*4096 tokens
#define NEXP  64

// Workspace layout (floats):
//   ws[0..63]   : expert load sums
//   ws[64]      : sum of z^2
//   ws[66]      : block-done counter (int)
//   ws[128 ..]  : w_t transposed gate weights [1024][64]
//
// d_out layout (floats, out_size = 65537):
//   [0, 32768)      top-2 renormalized scores [token][2]
//   [32768, 65536)  top-2 expert indices as floats [token][2]
//   [65536]         total_loss

// ---------------------------------------------------------------------------
// prep: tiled transpose gate_w [64][1024] -> w_t [1024][64]; zero accumulators
// ---------------------------------------------------------------------------
__global__ void moe_prep(const float* __restrict__ gw, float* __restrict__ ws) {
    __shared__ float tile[64][65];
    const int b = blockIdx.x;
    const int tid = threadIdx.x;         // 256
    if (b == 0 && tid < 128) ws[tid] = 0.f;
#pragma unroll
    for (int it = 0; it < 16; ++it) {
        int idx = it * 256 + tid;
        int e = idx >> 6, kk = idx & 63;
        tile[e][kk] = gw[e * 1024 + b * 64 + kk];
    }
    __syncthreads();
#pragma unroll
    for (int it = 0; it < 16; ++it) {
        int idx = it * 256 + tid;
        int kk = idx >> 6, e = idx & 63;
        ws[128 + (b * 64 + kk) * 64 + e] = tile[e][kk];
    }
}

// ---------------------------------------------------------------------------
// partial fold helpers (unchanged, proven): store/add a wave's 64t x 64e
// partial (8t x 8e per lane) into a stride-68 buffer.
// ---------------------------------------------------------------------------
__device__ __forceinline__ void pstore(float* B, const float (&a)[8][8],
                                       int tg, int eg) {
#pragma unroll
    for (int i = 0; i < 8; ++i) {
        float* p = B + (tg + 8 * i) * 68 + (eg << 3);
        *(float4*)(p)     = make_float4(a[i][0], a[i][1], a[i][2], a[i][3]);
        *(float4*)(p + 4) = make_float4(a[i][4], a[i][5], a[i][6], a[i][7]);
    }
}
__device__ __forceinline__ void padd(float* B, const float (&a)[8][8],
                                     int tg, int eg) {
#pragma unroll
    for (int i = 0; i < 8; ++i) {
        float* p = B + (tg + 8 * i) * 68 + (eg << 3);
        float4 v0 = *(float4*)(p);
        float4 v1 = *(float4*)(p + 4);
        v0.x += a[i][0]; v0.y += a[i][1]; v0.z += a[i][2]; v0.w += a[i][3];
        v1.x += a[i][4]; v1.y += a[i][5]; v1.z += a[i][6]; v1.w += a[i][7];
        *(float4*)(p)     = v0;
        *(float4*)(p + 4) = v1;
    }
}

// ---------------------------------------------------------------------------
// main: latency-restructured fp32 GEMM. Round-1 post-mortem: step time 8355
// cyc vs VALU wall 2048 + LDS wall ~3400 -> barrier/latency-bound. Fixes:
//  (1) double-buffered x slab, ONE barrier per step (was 2);
//  (2) w bypasses LDS entirely: per-wave JIT global_load_dwordx4 from the
//      L2-hot 256 KB wt (8-lane broadcast per address) -> LDS reads halve
//      to 8/wave/step, LDS wall ~1700 < VALU wall 2048;
//  (3) x global load issued 2 steps ahead of its LDS write (T14 split);
//      slab is packed [64][64] with 16B-granule XOR swizzle gs = g^(row&7)
//      so the 8-row read fan hits 8 distinct bank-quads (conflict-free).
// Per-wave k order (s*64+wv*4+u) and i->u->j FMA nest unchanged -> partials
// bit-identical -> fold + epilogue kept verbatim (absmax 0 preserved).
// ---------------------------------------------------------------------------
__launch_bounds__(1024, 4)
__global__ void moe_main(const float* __restrict__ x,
                         const float* __restrict__ wt,     // [1024][64]
                         float* __restrict__ acc_ws,
                         float* __restrict__ out) {
    __shared__ float xs[2 * 4352];       // two x slabs; also fold scratch (68-stride)
    __shared__ float sc[64 * 68];        // logits, stride 68
    __shared__ float row_inv[64];
    __shared__ float colpart[16][64];
    __shared__ int   is_last;

    const int tid  = threadIdx.x;
    const int lane = tid & 63;
    const int wv   = __builtin_amdgcn_readfirstlane(tid >> 6);   // 0..15 k-granule
    const int tg   = lane & 7;           // token sub-row: t = tg + 8i
    const int eg   = lane >> 3;          // expert octet: e = eg*8 + j
    const int tok0 = blockIdx.x << 6;

    // ---- x staging map: thread -> slot(row=tid>>4, gs=tid&15);
    //      slot holds k-granule gs ^ (row & 7) of the 64-k slab
    const int srow = tid >> 4;
    const int sgs  = tid & 15;
    const float* gx = x + (((size_t)(tok0 + srow)) << 10) + ((sgs ^ (srow & 7)) << 2);
    const int wloc = (srow << 6) + (sgs << 2);       // packed [64][64]

    // ---- w direct-load base: wt[(s*64 + wv*4 + u)][eg*8 ...]
    const float* gw0 = wt + (wv << 8) + (eg << 3);   // wv*4 rows * 64

    // ---- per-lane x read offset: row tg+8i, slot granule wv ^ tg
    const int xoff = (tg << 6) + ((wv ^ tg) << 2);   // + i*512 (imm)

    float acc[8][8];
#pragma unroll
    for (int i = 0; i < 8; ++i)
#pragma unroll
        for (int j = 0; j < 8; ++j) acc[i][j] = 0.f;

    // ---- prologue: stage step 0 into slab 0; prefetch step 1 into regs
    float4 px = *(const float4*)gx;
    *(float4*)(xs + wloc) = px;
    px = *(const float4*)(gx + 64);
    __syncthreads();

    int rb = 0;                          // read-slab float offset (0 / 4352)
#pragma unroll 1
    for (int s = 0; s < 16; ++s) {
        // JIT w fragment for this step (L2-hot, 8-lane broadcast per addr)
        const float* gwr = gw0 + (s << 12);          // + s*64 rows
        float4 w0a = *(const float4*)(gwr);
        float4 w0b = *(const float4*)(gwr + 4);
        float4 w1a = *(const float4*)(gwr + 64);
        float4 w1b = *(const float4*)(gwr + 68);
        float4 w2a = *(const float4*)(gwr + 128);
        float4 w2b = *(const float4*)(gwr + 132);
        float4 w3a = *(const float4*)(gwr + 192);
        float4 w3b = *(const float4*)(gwr + 196);
        // stage next step's x (loaded 2 steps ago) into the free slab,
        // then issue the global load for step s+2
        if (s < 15) {
            *(float4*)(xs + (rb ^ 4352) + wloc) = px;
            if (s < 14) px = *(const float4*)(gx + ((s + 2) << 6));
        }
        const float wa[4][8] = {
            {w0a.x, w0a.y, w0a.z, w0a.w, w0b.x, w0b.y, w0b.z, w0b.w},
            {w1a.x, w1a.y, w1a.z, w1a.w, w1b.x, w1b.y, w1b.z, w1b.w},
            {w2a.x, w2a.y, w2a.z, w2a.w, w2b.x, w2b.y, w2b.z, w2b.w},
            {w3a.x, w3a.y, w3a.z, w3a.w, w3b.x, w3b.y, w3b.z, w3b.w}};
        const float* rdp = xs + rb + xoff;
#pragma unroll
        for (int i = 0; i < 8; ++i) {
            float4 xc = *(const float4*)(rdp + (i << 9));   // x[tg+8i][4k]
            float xa[4] = {xc.x, xc.y, xc.z, xc.w};
#pragma unroll
            for (int u = 0; u < 4; ++u) {
                float xv = xa[u];
#pragma unroll
                for (int j = 0; j < 8; ++j)
                    acc[i][j] = fmaf(xv, wa[u][j], acc[i][j]);
            }
        }
        __syncthreads();                 // slab s done; slab s+1 writes drained
        rb ^= 4352;
    }

    // ---- fold 16 k-partials into sc via 3 accumulation chains (verbatim)
    float* fb0 = xs;                     // stride-68 scratch over slab 0
    float* fb1 = xs + 4352;              // stride-68 scratch over slab 1
    if      (wv == 0) pstore(sc,  acc, tg, eg);
    else if (wv == 1) pstore(fb0, acc, tg, eg);
    else if (wv == 2) pstore(fb1, acc, tg, eg);
    __syncthreads();
    if      (wv == 3) padd(sc,  acc, tg, eg);
    else if (wv == 4) padd(fb0, acc, tg, eg);
    else if (wv == 5) padd(fb1, acc, tg, eg);
    __syncthreads();
    if      (wv == 6) padd(sc,  acc, tg, eg);
    else if (wv == 7) padd(fb0, acc, tg, eg);
    else if (wv == 8) padd(fb1, acc, tg, eg);
    __syncthreads();
    if      (wv == 9)  padd(sc,  acc, tg, eg);
    else if (wv == 10) padd(fb0, acc, tg, eg);
    else if (wv == 11) padd(fb1, acc, tg, eg);
    __syncthreads();
    if      (wv == 12) padd(sc,  acc, tg, eg);
    else if (wv == 13) padd(fb0, acc, tg, eg);
    else if (wv == 14) padd(fb1, acc, tg, eg);
    __syncthreads();
    if (wv == 15) padd(sc, acc, tg, eg);
    __syncthreads();
    {   // sc += fb0 + fb1 (vectorized, all 1024 threads)
        const int row = tid >> 4, g = tid & 15;
        float* ps = sc + row * 68 + (g << 2);
        float4 a  = *(float4*)ps;
        float4 bx = *(const float4*)(fb0 + row * 68 + (g << 2));
        float4 bw = *(const float4*)(fb1 + row * 68 + (g << 2));
        a.x += bx.x + bw.x; a.y += bx.y + bw.y;
        a.z += bx.z + bw.z; a.w += bx.w + bw.w;
        *(float4*)ps = a;
    }
    __syncthreads();

    // ---- per-token epilogue (serial, proven absmax 0)
    if (tid < 64) {
        const int r = tid;
        const float* srow_p = sc + r * 68;
        float v1 = -1e30f, v2 = -1e30f;
        int i1 = 0, i2 = 0;
        for (int j = 0; j < 64; ++j) {
            float l = srow_p[j];
            if (l > v1)      { v2 = v1; i2 = i1; v1 = l; i1 = j; }
            else if (l > v2) { v2 = l; i2 = j; }
        }
        float m = v1;
        float ssum = 0.f;
        for (int j = 0; j < 64; ++j) {
            float ev = expf(srow_p[j] - m);
            ssum += ev;
            sc[r * 68 + j] = ev;
        }
        float inv = 1.f / ssum;
        row_inv[r] = inv;
        float z = m + logf(ssum);
        float zsq = z * z;
#pragma unroll
        for (int off = 32; off > 0; off >>= 1) zsq += __shfl_down(zsq, off);
        if (lane == 0) atomicAdd(acc_ws + 64, zsq);

        float p1s = inv;                        // exp(v1-m) == 1
        float p2s = expf(v2 - m) * inv;
        float bb  = expf(p2s - p1s);
        float s1 = 1.f / (1.f + bb);
        float s2 = bb * s1;
        int t = tok0 + r;
        out[2 * t]     = s1;
        out[2 * t + 1] = s2;
        out[2 * T_TOK + 2 * t]     = (float)i1;
        out[2 * T_TOK + 2 * t + 1] = (float)i2;
    }
    __syncthreads();

    // ---- expert load column sums (16 row-groups of 4 rows)
    {
        int e  = tid & 63;
        int rg = tid >> 6;                      // 0..15
        float sum = 0.f;
#pragma unroll
        for (int r2 = 0; r2 < 4; ++r2) {
            int row = (rg << 2) + r2;
            sum += sc[row * 68 + e] * row_inv[row];
        }
        colpart[rg][e] = sum;
    }
    __syncthreads();
    if (tid < 64) {
        float tot = 0.f;
#pragma unroll
        for (int rg = 0; rg < 16; ++rg) tot += colpart[rg][tid];
        atomicAdd(acc_ws + tid, tot);           // device-scope
    }

    // ---- last-block finalize
    __syncthreads();
    if (tid == 0) {
        __threadfence();
        int old = __hip_atomic_fetch_add((int*)(acc_ws + 66), 1,
                                         __ATOMIC_ACQ_REL, __HIP_MEMORY_SCOPE_AGENT);
        is_last = (old == 255) ? 1 : 0;
    }
    __syncthreads();
    if (is_last && tid < 64) {
        __threadfence();
        float load = __hip_atomic_load(acc_ws + tid, __ATOMIC_RELAXED,
                                       __HIP_MEMORY_SCOPE_AGENT) * (1.f / 16384.f);
        float d = load - (1.f / 64.f);
        float v = d * d;
#pragma unroll
        for (int off = 32; off > 0; off >>= 1) v += __shfl_down(v, off);
        if (tid == 0) {
            float zsum = __hip_atomic_load(acc_ws + 64, __ATOMIC_RELAXED,
                                           __HIP_MEMORY_SCOPE_AGENT);
            float lb = 0.01f * 64.f * v;
            float zl = 1e-4f * zsum * (1.f / 16384.f);
            out[4 * T_TOK] = lb + zl;
        }
    }
}

extern "C" void kernel_launch(void* const* d_in, const int* in_sizes, int n_in,
                              void* d_out, int out_size, void* d_ws, size_t ws_size,
                              hipStream_t stream) {
    const float* x  = (const float*)d_in[0];   // [4,4096,1024] fp32
    const float* gw = (const float*)d_in[1];   // [64,1024] fp32
    float* out = (float*)d_out;                // 65537 fp32
    float* ws  = (float*)d_ws;

    moe_prep<<<16, 256, 0, stream>>>(gw, ws);
    moe_main<<<256, 1024, 0, stream>>>(x, ws + 128, ws, out);
}